// Round 1
// baseline (2284.644 us; speedup 1.0000x reference)
//
#include <hip/hip_runtime.h>
#include <math.h>

// ---------------------------------------------------------------------------
// RecurrentEncoder: LSTM (B=256, D=2048, H=2048, T=32) + emission head (K=64)
// Round 0: multi-launch bf16-MFMA implementation.
//   - per-tick fused kernel: g = xg + h@W_hh^T  -> gates -> (c,h) update
//   - block b owns 8 hidden units (32 gate-columns), C-tile 256x32, K=2048
//   - emission fe = H_all @ W_fe^T batched over all 32 ticks at the end
// ---------------------------------------------------------------------------

typedef short  short8  __attribute__((ext_vector_type(8)));   // 8 x bf16
typedef float  floatx4 __attribute__((ext_vector_type(4)));

#define BB 256
#define HH 2048
#define G4 8192
#define KK 64
#define TT 32

__device__ __forceinline__ unsigned short f2bf(float f) {
  union { float f; unsigned int u; } v; v.f = f;
  unsigned int u = v.u;
  u += 0x7fffu + ((u >> 16) & 1u);   // round-to-nearest-even
  return (unsigned short)(u >> 16);
}
__device__ __forceinline__ float sigmoidf_(float x) { return 1.0f / (1.0f + __expf(-x)); }
__device__ __forceinline__ float softplusf_(float x) {
  return (x > 20.0f) ? x : log1pf(__expf(x));
}

// fp32 -> bf16 conversion, 4 elems/thread
__global__ void cvt_kernel(const float* __restrict__ in,
                           unsigned short* __restrict__ out, int n4) {
  int i = blockIdx.x * blockDim.x + threadIdx.x;
  if (i >= n4) return;
  float4 v = reinterpret_cast<const float4*>(in)[i];
  ushort4 o;
  o.x = f2bf(v.x); o.y = f2bf(v.y); o.z = f2bf(v.z); o.w = f2bf(v.w);
  reinterpret_cast<ushort4*>(out)[i] = o;
}

// Core: 256x32 C-tile, K=2048, 4 waves (wave w -> rows [64w,64w+64)).
// A: row-major (row stride 2048 bf16 = 256 short8), rows = batch.
// W: row-major along K; wrow0/wrow1 are the W-rows for col-tiles ct=0/1
//    at n = lane&15. Register-double-buffered fragment loads.
__device__ __forceinline__ void mfma_core(const short8* __restrict__ A,
                                          const short8* __restrict__ W,
                                          int arow, int wrow0, int wrow1,
                                          int l4, floatx4 acc[4][2]) {
  int koff = l4;  // short8 units: k/8 + kslab
  short8 a_cur[4], b0, b1;
  b0 = W[wrow0 * 256 + koff];
  b1 = W[wrow1 * 256 + koff];
#pragma unroll
  for (int rt = 0; rt < 4; rt++) a_cur[rt] = A[(arow + rt * 16) * 256 + koff];
  for (int k0 = 0; k0 < 2048; k0 += 32) {
    const int koff2 = (k0 + 32 < 2048) ? (koff + 4) : l4;  // last iter: wrap (discarded)
    short8 bn0 = W[wrow0 * 256 + koff2];
    short8 bn1 = W[wrow1 * 256 + koff2];
    short8 an[4];
#pragma unroll
    for (int rt = 0; rt < 4; rt++) an[rt] = A[(arow + rt * 16) * 256 + koff2];
#pragma unroll
    for (int rt = 0; rt < 4; rt++) {
      acc[rt][0] = __builtin_amdgcn_mfma_f32_16x16x32_bf16(a_cur[rt], b0, acc[rt][0], 0, 0, 0);
      acc[rt][1] = __builtin_amdgcn_mfma_f32_16x16x32_bf16(a_cur[rt], b1, acc[rt][1], 0, 0, 0);
    }
#pragma unroll
    for (int rt = 0; rt < 4; rt++) a_cur[rt] = an[rt];
    b0 = bn0; b1 = bn1;
    koff = koff2;
  }
}

// xg = x @ W_ih^T + b_ih + b_hh   (256 x 8192), block -> 32 contiguous cols
__global__ __launch_bounds__(256) void xg_gemm(const unsigned short* __restrict__ Xb,
                                               const unsigned short* __restrict__ Wih,
                                               const float* __restrict__ b_ih,
                                               const float* __restrict__ b_hh,
                                               float* __restrict__ xg) {
  const int lane = threadIdx.x & 63, wave = threadIdx.x >> 6;
  const int l15 = lane & 15, l4 = lane >> 4;
  const int colbase = blockIdx.x * 32;
  floatx4 acc[4][2];
  floatx4 z4 = {0.f, 0.f, 0.f, 0.f};
#pragma unroll
  for (int rt = 0; rt < 4; rt++) { acc[rt][0] = z4; acc[rt][1] = z4; }
  mfma_core(reinterpret_cast<const short8*>(Xb), reinterpret_cast<const short8*>(Wih),
            wave * 64 + l15, colbase + l15, colbase + 16 + l15, l4, acc);
#pragma unroll
  for (int ct = 0; ct < 2; ct++) {
    const int col = colbase + ct * 16 + l15;
    const float bias = b_ih[col] + b_hh[col];
#pragma unroll
    for (int rt = 0; rt < 4; rt++) {
#pragma unroll
      for (int r = 0; r < 4; r++) {
        const int row = wave * 64 + rt * 16 + l4 * 4 + r;
        xg[row * G4 + col] = acc[rt][ct][r] + bias;
      }
    }
  }
}

// One LSTM tick: g = xg + h@W_hh^T; gates; c,h update.
// Block b owns units [8b,8b+8). col-tile ct=0 -> gates {0,1} (i,f),
// ct=1 -> gates {2,3} (g,o); lane pairs (l15, l15+8) exchange via shfl_xor(8).
__global__ __launch_bounds__(256) void tick_kernel(const unsigned short* __restrict__ Hin,
                                                   unsigned short* __restrict__ Hout,
                                                   const unsigned short* __restrict__ Whh,
                                                   const float* __restrict__ xg,
                                                   float* __restrict__ c,
                                                   float* __restrict__ out_h,
                                                   float* __restrict__ out_c,
                                                   int last) {
  const int lane = threadIdx.x & 63, wave = threadIdx.x >> 6;
  const int l15 = lane & 15, l4 = lane >> 4;
  const int ub = blockIdx.x * 8;
  const int gate0 = l15 >> 3;      // 0 or 1
  const int up = l15 & 7;          // unit within block
  const int wrow0 = gate0 * HH + ub + up;        // gate {0,1} row
  const int wrow1 = (gate0 + 2) * HH + ub + up;  // gate {2,3} row
  floatx4 acc[4][2];
  floatx4 z4 = {0.f, 0.f, 0.f, 0.f};
#pragma unroll
  for (int rt = 0; rt < 4; rt++) { acc[rt][0] = z4; acc[rt][1] = z4; }
  mfma_core(reinterpret_cast<const short8*>(Hin), reinterpret_cast<const short8*>(Whh),
            wave * 64 + l15, wrow0, wrow1, l4, acc);
  // epilogue: wrow indices double as xg column indices
#pragma unroll
  for (int rt = 0; rt < 4; rt++) {
#pragma unroll
    for (int r = 0; r < 4; r++) {
      const int row = wave * 64 + rt * 16 + l4 * 4 + r;
      const float gA = acc[rt][0][r] + xg[row * G4 + wrow0];  // i (l15<8) / f (l15>=8)
      const float gB = acc[rt][1][r] + xg[row * G4 + wrow1];  // g (l15<8) / o (l15>=8)
      const float fpre = __shfl_xor(gA, 8, 64);
      const float opre = __shfl_xor(gB, 8, 64);
      if (l15 < 8) {
        const int idx = row * HH + ub + up;
        const float iv = sigmoidf_(gA);
        const float gv = tanhf(gB);
        const float fv = sigmoidf_(fpre);
        const float ov = sigmoidf_(opre);
        const float cold = c[idx];
        const float cnew = fv * cold + iv * gv;
        const float hnew = ov * tanhf(cnew);
        c[idx] = cnew;
        Hout[idx] = f2bf(hnew);
        if (last) { out_h[idx] = hnew; out_c[idx] = cnew; }
      }
    }
  }
}

// fe = H_all @ W_fe^T + b_fe  for all 32 ticks at once (8192 x 128)
__global__ __launch_bounds__(256) void fe_gemm(const unsigned short* __restrict__ Hall1,
                                               const unsigned short* __restrict__ Wfe,
                                               const float* __restrict__ b_fe,
                                               float* __restrict__ fe) {
  const int lane = threadIdx.x & 63, wave = threadIdx.x >> 6;
  const int l15 = lane & 15, l4 = lane >> 4;
  const int rowbase = blockIdx.x * 256;
  const int colbase = blockIdx.y * 32;
  floatx4 acc[4][2];
  floatx4 z4 = {0.f, 0.f, 0.f, 0.f};
#pragma unroll
  for (int rt = 0; rt < 4; rt++) { acc[rt][0] = z4; acc[rt][1] = z4; }
  mfma_core(reinterpret_cast<const short8*>(Hall1), reinterpret_cast<const short8*>(Wfe),
            rowbase + wave * 64 + l15, colbase + l15, colbase + 16 + l15, l4, acc);
#pragma unroll
  for (int ct = 0; ct < 2; ct++) {
    const int col = colbase + ct * 16 + l15;
    const float bias = b_fe[col];
#pragma unroll
    for (int rt = 0; rt < 4; rt++) {
#pragma unroll
      for (int r = 0; r < 4; r++) {
        const int row = rowbase + wave * 64 + rt * 16 + l4 * 4 + r;
        fe[row * 128 + col] = acc[rt][ct][r] + bias;
      }
    }
  }
}

// z = eps*softplus(fe[:,64:]-5) + fe[:,:64]; outputs laid out (B,K,T)
__global__ void z_kernel(const float* __restrict__ eps, const float* __restrict__ fe,
                         float* __restrict__ out) {
  const int tid = blockIdx.x * blockDim.x + threadIdx.x;  // 524288 = T*B*K
  const int t = tid >> 14;
  const int b = (tid >> 6) & 255;
  const int k = tid & 63;
  const int frow = t * 256 + b;
  const float mus = fe[frow * 128 + k];
  const float sig = softplusf_(fe[frow * 128 + 64 + k] - 5.0f);
  const float z = eps[tid] * sig + mus;
  const int o = (b * KK + k) * TT + t;
  out[o] = z;
  out[524288 + o] = mus;
  out[2 * 524288 + o] = sig;
}

extern "C" void kernel_launch(void* const* d_in, const int* in_sizes, int n_in,
                              void* d_out, int out_size, void* d_ws, size_t ws_size,
                              hipStream_t stream) {
  const float* x    = (const float*)d_in[0];
  const float* eps  = (const float*)d_in[1];
  const float* W_ih = (const float*)d_in[2];
  const float* W_hh = (const float*)d_in[3];
  const float* b_ih = (const float*)d_in[4];
  const float* b_hh = (const float*)d_in[5];
  const float* W_fe = (const float*)d_in[6];
  const float* b_fe = (const float*)d_in[7];
  float* out = (float*)d_out;

  const size_t BH  = (size_t)BB * HH;   // 524288
  const size_t BKT = (size_t)BB * KK * TT;  // 524288

  char* p = (char*)d_ws;
  auto nxt = [&](size_t bytes) -> char* {
    char* r = p; p += (bytes + 255) & ~(size_t)255; return r;
  };
  unsigned short* Wbig = (unsigned short*)nxt((size_t)G4 * HH * 2);  // W_ih then W_hh (bf16)
  float*          xg   = (float*)nxt((size_t)BB * G4 * 4);
  float*          c    = (float*)nxt(BH * 4);
  unsigned short* Hall = (unsigned short*)nxt((size_t)(TT + 1) * BH * 2);  // slot 0 = h0 = 0
  unsigned short* Xb   = (unsigned short*)nxt(BH * 2);
  unsigned short* Wfeb = (unsigned short*)nxt((size_t)128 * HH * 2);
  float*          fe   = (float*)nxt((size_t)(TT * BB) * 128 * 4);

  hipMemsetAsync(c, 0, BH * 4, stream);
  hipMemsetAsync(Hall, 0, BH * 2, stream);  // slot 0 only

  cvt_kernel<<<(int)(BH / 4 / 256), 256, 0, stream>>>(x, Xb, (int)(BH / 4));
  cvt_kernel<<<128 * HH / 4 / 256, 256, 0, stream>>>(W_fe, Wfeb, 128 * HH / 4);
  cvt_kernel<<<G4 * HH / 4 / 256, 256, 0, stream>>>(W_ih, Wbig, G4 * HH / 4);
  xg_gemm<<<256, 256, 0, stream>>>(Xb, Wbig, b_ih, b_hh, xg);
  cvt_kernel<<<G4 * HH / 4 / 256, 256, 0, stream>>>(W_hh, Wbig, G4 * HH / 4);

  for (int t = 0; t < TT; t++) {
    tick_kernel<<<256, 256, 0, stream>>>(
        Hall + (size_t)t * BH, Hall + (size_t)(t + 1) * BH, Wbig, xg, c,
        out + 3 * BKT, out + 3 * BKT + BH, (int)(t == TT - 1));
  }

  fe_gemm<<<dim3(32, 4), 256, 0, stream>>>(Hall + BH, Wfeb, b_fe, fe);
  z_kernel<<<(int)(BKT / 256), 256, 0, stream>>>(eps, fe, out);
}

// Round 2
// 1530.408 us; speedup vs baseline: 1.4928x; 1.4928x over previous
//
#include <hip/hip_runtime.h>
#include <math.h>

// ---------------------------------------------------------------------------
// RecurrentEncoder: LSTM (B=256, D=2048, H=2048, T=32) + emission head (K=64)
// Round 2: 64x128 C-tiles, 512-thr blocks (8 waves/CU), LDS-staged double-
// buffered K-loop (BK=64), gate-interleaved (permuted) weight layout so the
// cell update fuses into the tick kernel epilogue.
// ---------------------------------------------------------------------------

typedef short  short8  __attribute__((ext_vector_type(8)));   // 8 x bf16
typedef float  floatx4 __attribute__((ext_vector_type(4)));

#define BB 256
#define HH 2048
#define G4 8192
#define KK 64
#define TT 32
#define DK 2048   // K depth of all big GEMMs

__device__ __forceinline__ unsigned short f2bf(float f) {
  union { float f; unsigned int u; } v; v.f = f;
  unsigned int u = v.u;
  u += 0x7fffu + ((u >> 16) & 1u);   // round-to-nearest-even
  return (unsigned short)(u >> 16);
}
__device__ __forceinline__ float sigmoidf_(float x) { return 1.0f / (1.0f + __expf(-x)); }
__device__ __forceinline__ float softplusf_(float x) {
  return (x > 20.0f) ? x : log1pf(__expf(x));
}

// plain fp32 -> bf16 conversion, 4 elems/thread
__global__ void cvt_kernel(const float* __restrict__ in,
                           unsigned short* __restrict__ out, int n4) {
  int i = blockIdx.x * blockDim.x + threadIdx.x;
  if (i >= n4) return;
  float4 v = reinterpret_cast<const float4*>(in)[i];
  ushort4 o;
  o.x = f2bf(v.x); o.y = f2bf(v.y); o.z = f2bf(v.z); o.w = f2bf(v.w);
  reinterpret_cast<ushort4*>(out)[i] = o;
}

// permuting cvt for W_ih / W_hh: out row q = unit*4 + gate  <-  in row gate*2048 + unit
// 8 elems per thread along k.
__global__ void cvt_perm_kernel(const float* __restrict__ in,
                                unsigned short* __restrict__ out) {
  int tid = blockIdx.x * 256 + threadIdx.x;   // 8192 * 256 total
  int q  = tid >> 8;
  int k8 = tid & 255;
  int u = q >> 2, g = q & 3;
  const float* src = in + (size_t)(g * HH + u) * DK + k8 * 8;
  float4 a = reinterpret_cast<const float4*>(src)[0];
  float4 b = reinterpret_cast<const float4*>(src)[1];
  short8 o;
  o[0] = f2bf(a.x); o[1] = f2bf(a.y); o[2] = f2bf(a.z); o[3] = f2bf(a.w);
  o[4] = f2bf(b.x); o[5] = f2bf(b.y); o[6] = f2bf(b.z); o[7] = f2bf(b.w);
  *reinterpret_cast<short8*>(out + (size_t)q * DK + k8 * 8) = o;
}

// ---------------------------------------------------------------------------
// GEMM core: C-tile 64 rows x 128 cols, K = 2048, block = 512 threads
// (8 waves in a 2x4 grid of 32x32 wave-tiles). LDS staging, BK = 64:
//   Abuf [8 kslab][64 row][16B]  = 8 KB
//   Wbuf [8 kslab][128 col][16B] = 16 KB       (double-buffered -> 48 KB)
// Per stage each thread round-trips 3 16-B chunks (coalesced 128-B runs in
// global, conflict-free LDS). Prefetch for stage s+1 is issued after the
// "buffer ready" barrier so the MFMA block covers its latency.
// ---------------------------------------------------------------------------
__device__ __forceinline__ void gemm_core(const unsigned short* __restrict__ A,
                                          const unsigned short* __restrict__ W,
                                          int rb, int cb, char* smem,
                                          floatx4 acc[2][2]) {
  const int t = threadIdx.x;
  const int lane = t & 63, wave = t >> 6;
  const int rg = wave >> 2, cg = wave & 3;
  const int l15 = lane & 15, l4 = lane >> 4;

  const unsigned short* ga0 = A + (size_t)(rb + (t >> 3)) * DK + (t & 7) * 8;
  const unsigned short* ga1 = W + (size_t)(cb + (t >> 3)) * DK + (t & 7) * 8;
  const unsigned short* ga2 = W + (size_t)(cb + 64 + (t >> 3)) * DK + (t & 7) * 8;
  const int ldsA  = (t & 7) * 1024 + (t >> 3) * 16;
  const int ldsW0 = 8192 + (t & 7) * 2048 + (t >> 3) * 16;
  const int ldsW1 = ldsW0 + 1024;

  const int abase = l4 * 1024 + (rg * 32 + l15) * 16;          // + kk*4096 + rt*256
  const int wbase = 8192 + l4 * 2048 + (cg * 32 + l15) * 16;   // + kk*8192 + ct*256

  short8 r0 = *reinterpret_cast<const short8*>(ga0);
  short8 r1 = *reinterpret_cast<const short8*>(ga1);
  short8 r2 = *reinterpret_cast<const short8*>(ga2);
  ga0 += 64; ga1 += 64; ga2 += 64;

  for (int s = 0; s < 32; ++s) {
    char* buf = smem + (s & 1) * 24576;
    __syncthreads();   // (a) prev readers of this buffer done; drains prefetch
    *reinterpret_cast<short8*>(buf + ldsA)  = r0;
    *reinterpret_cast<short8*>(buf + ldsW0) = r1;
    *reinterpret_cast<short8*>(buf + ldsW1) = r2;
    __syncthreads();   // (b) buffer ready (lgkm only)
    if (s < 31) {      // prefetch next stage; latency covered by MFMAs below
      r0 = *reinterpret_cast<const short8*>(ga0);
      r1 = *reinterpret_cast<const short8*>(ga1);
      r2 = *reinterpret_cast<const short8*>(ga2);
      ga0 += 64; ga1 += 64; ga2 += 64;
    }
#pragma unroll
    for (int kk = 0; kk < 2; ++kk) {
      short8 af0 = *reinterpret_cast<const short8*>(buf + abase + kk * 4096);
      short8 af1 = *reinterpret_cast<const short8*>(buf + abase + kk * 4096 + 256);
      short8 bf0 = *reinterpret_cast<const short8*>(buf + wbase + kk * 8192);
      short8 bf1 = *reinterpret_cast<const short8*>(buf + wbase + kk * 8192 + 256);
      acc[0][0] = __builtin_amdgcn_mfma_f32_16x16x32_bf16(af0, bf0, acc[0][0], 0, 0, 0);
      acc[0][1] = __builtin_amdgcn_mfma_f32_16x16x32_bf16(af0, bf1, acc[0][1], 0, 0, 0);
      acc[1][0] = __builtin_amdgcn_mfma_f32_16x16x32_bf16(af1, bf0, acc[1][0], 0, 0, 0);
      acc[1][1] = __builtin_amdgcn_mfma_f32_16x16x32_bf16(af1, bf1, acc[1][1], 0, 0, 0);
    }
  }
}

// ---------------------------------------------------------------------------
// One LSTM tick. Gate columns are permuted (q = u*4+g) so the 128-col tile
// holds 32 complete units; pre-activations round-trip through LDS (reusing
// the staging buffers) for the cell update.
// ---------------------------------------------------------------------------
__global__ __launch_bounds__(512, 2) void tick_kernel(
    const unsigned short* __restrict__ Hin, unsigned short* __restrict__ Hout,
    const unsigned short* __restrict__ Whh, const float* __restrict__ xg,
    float* __restrict__ c, float* __restrict__ out_h, float* __restrict__ out_c,
    int last) {
  __shared__ char smem[49152];
  const int rb = blockIdx.y * 64;
  const int cb = blockIdx.x * 128;
  floatx4 acc[2][2];
  floatx4 z4 = {0.f, 0.f, 0.f, 0.f};
  acc[0][0] = z4; acc[0][1] = z4; acc[1][0] = z4; acc[1][1] = z4;
  gemm_core(Hin, Whh, rb, cb, smem, acc);

  const int t = threadIdx.x, lane = t & 63, wave = t >> 6;
  const int rg = wave >> 2, cg = wave & 3, l15 = lane & 15, l4 = lane >> 4;
  __syncthreads();   // staging buffers now reusable
  float* g = (float*)smem;  // 64 x 128 fp32
#pragma unroll
  for (int rt = 0; rt < 2; ++rt)
#pragma unroll
    for (int ct = 0; ct < 2; ++ct)
#pragma unroll
      for (int r = 0; r < 4; ++r) {
        int row = rg * 32 + rt * 16 + l4 * 4 + r;
        int col = cg * 32 + ct * 16 + l15;
        g[row * 128 + col] = acc[rt][ct][r] + xg[(size_t)(rb + row) * G4 + cb + col];
      }
  __syncthreads();
  const int u = t & 31, rq = t >> 5;
#pragma unroll
  for (int j = 0; j < 4; ++j) {
    int row = rq * 4 + j;
    floatx4 gv = *reinterpret_cast<floatx4*>(g + row * 128 + u * 4);  // i,f,g,o
    float iv = sigmoidf_(gv[0]);
    float fv = sigmoidf_(gv[1]);
    float gg = tanhf(gv[2]);
    float ov = sigmoidf_(gv[3]);
    size_t ci = (size_t)(rb + row) * HH + (cb >> 2) + u;
    float cold = c[ci];
    float cnew = fv * cold + iv * gg;
    float hnew = ov * tanhf(cnew);
    c[ci] = cnew;
    Hout[ci] = (unsigned short)f2bf(hnew);
    if (last) { out_h[ci] = hnew; out_c[ci] = cnew; }
  }
}

// xg = x @ W_ih^T(permuted) + b_ih + b_hh   -> xg[256][8192] (q-ordered cols)
__global__ __launch_bounds__(512, 2) void xg_kernel(
    const unsigned short* __restrict__ Xb, const unsigned short* __restrict__ Wihb,
    const float* __restrict__ b_ih, const float* __restrict__ b_hh,
    float* __restrict__ xg) {
  __shared__ char smem[49152];
  const int rb = blockIdx.y * 64;
  const int cb = blockIdx.x * 128;
  floatx4 acc[2][2];
  floatx4 z4 = {0.f, 0.f, 0.f, 0.f};
  acc[0][0] = z4; acc[0][1] = z4; acc[1][0] = z4; acc[1][1] = z4;
  gemm_core(Xb, Wihb, rb, cb, smem, acc);

  const int lane = threadIdx.x & 63, wave = threadIdx.x >> 6;
  const int rg = wave >> 2, cg = wave & 3, l15 = lane & 15, l4 = lane >> 4;
#pragma unroll
  for (int rt = 0; rt < 2; ++rt)
#pragma unroll
    for (int ct = 0; ct < 2; ++ct) {
      int col = cg * 32 + ct * 16 + l15;
      int q = cb + col;
      int gi = q & 3, ui = q >> 2;
      float bias = b_ih[gi * HH + ui] + b_hh[gi * HH + ui];
#pragma unroll
      for (int r = 0; r < 4; ++r) {
        int row = rg * 32 + rt * 16 + l4 * 4 + r;
        xg[(size_t)(rb + row) * G4 + q] = acc[rt][ct][r] + bias;
      }
    }
}

// fe = H_all @ W_fe^T + b_fe   (8192 x 128, natural col order)
__global__ __launch_bounds__(512, 2) void fe_kernel(
    const unsigned short* __restrict__ Hall1, const unsigned short* __restrict__ Wfeb,
    const float* __restrict__ b_fe, float* __restrict__ fe) {
  __shared__ char smem[49152];
  const int rb = blockIdx.y * 64;
  floatx4 acc[2][2];
  floatx4 z4 = {0.f, 0.f, 0.f, 0.f};
  acc[0][0] = z4; acc[0][1] = z4; acc[1][0] = z4; acc[1][1] = z4;
  gemm_core(Hall1, Wfeb, rb, 0, smem, acc);

  const int lane = threadIdx.x & 63, wave = threadIdx.x >> 6;
  const int rg = wave >> 2, cg = wave & 3, l15 = lane & 15, l4 = lane >> 4;
#pragma unroll
  for (int rt = 0; rt < 2; ++rt)
#pragma unroll
    for (int ct = 0; ct < 2; ++ct) {
      int col = cg * 32 + ct * 16 + l15;
      float bias = b_fe[col];
#pragma unroll
      for (int r = 0; r < 4; ++r) {
        int row = rg * 32 + rt * 16 + l4 * 4 + r;
        fe[(size_t)(rb + row) * 128 + col] = acc[rt][ct][r] + bias;
      }
    }
}

// z = eps*softplus(fe[:,64:]-5) + fe[:,:64]; outputs laid out (B,K,T)
__global__ void z_kernel(const float* __restrict__ eps, const float* __restrict__ fe,
                         float* __restrict__ out) {
  const int tid = blockIdx.x * blockDim.x + threadIdx.x;  // 524288 = T*B*K
  const int tt = tid >> 14;
  const int b = (tid >> 6) & 255;
  const int k = tid & 63;
  const int frow = tt * 256 + b;
  const float mus = fe[frow * 128 + k];
  const float sig = softplusf_(fe[frow * 128 + 64 + k] - 5.0f);
  const float z = eps[tid] * sig + mus;
  const int o = (b * KK + k) * TT + tt;
  out[o] = z;
  out[524288 + o] = mus;
  out[2 * 524288 + o] = sig;
}

extern "C" void kernel_launch(void* const* d_in, const int* in_sizes, int n_in,
                              void* d_out, int out_size, void* d_ws, size_t ws_size,
                              hipStream_t stream) {
  const float* x    = (const float*)d_in[0];
  const float* eps  = (const float*)d_in[1];
  const float* W_ih = (const float*)d_in[2];
  const float* W_hh = (const float*)d_in[3];
  const float* b_ih = (const float*)d_in[4];
  const float* b_hh = (const float*)d_in[5];
  const float* W_fe = (const float*)d_in[6];
  const float* b_fe = (const float*)d_in[7];
  float* out = (float*)d_out;

  const size_t BH  = (size_t)BB * HH;       // 524288
  const size_t BKT = (size_t)BB * KK * TT;  // 524288

  char* p = (char*)d_ws;
  auto nxt = [&](size_t bytes) -> char* {
    char* r = p; p += (bytes + 255) & ~(size_t)255; return r;
  };
  unsigned short* Wbig = (unsigned short*)nxt((size_t)G4 * HH * 2);  // W_ih then W_hh (bf16, permuted)
  float*          xg   = (float*)nxt((size_t)BB * G4 * 4);
  float*          c    = (float*)nxt(BH * 4);
  unsigned short* Hall = (unsigned short*)nxt((size_t)(TT + 1) * BH * 2);  // slot 0 = h0 = 0
  unsigned short* Xb   = (unsigned short*)nxt(BH * 2);
  unsigned short* Wfeb = (unsigned short*)nxt((size_t)128 * HH * 2);
  float*          fe   = (float*)nxt((size_t)(TT * BB) * 128 * 4);

  hipMemsetAsync(c, 0, BH * 4, stream);
  hipMemsetAsync(Hall, 0, BH * 2, stream);  // slot 0 only

  cvt_kernel<<<(int)(BH / 4 / 256), 256, 0, stream>>>(x, Xb, (int)(BH / 4));
  cvt_kernel<<<128 * HH / 4 / 256, 256, 0, stream>>>(W_fe, Wfeb, 128 * HH / 4);
  cvt_perm_kernel<<<8192, 256, 0, stream>>>(W_ih, Wbig);
  xg_kernel<<<dim3(64, 4), 512, 0, stream>>>(Xb, Wbig, b_ih, b_hh, xg);
  cvt_perm_kernel<<<8192, 256, 0, stream>>>(W_hh, Wbig);

  for (int t = 0; t < TT; t++) {
    tick_kernel<<<dim3(64, 4), 512, 0, stream>>>(
        Hall + (size_t)t * BH, Hall + (size_t)(t + 1) * BH, Wbig, xg, c,
        out + 3 * BKT, out + 3 * BKT + BH, (int)(t == TT - 1));
  }

  fe_kernel<<<dim3(1, 128), 512, 0, stream>>>(Hall + BH, Wfeb, b_fe, fe);
  z_kernel<<<(int)(BKT / 256), 256, 0, stream>>>(eps, fe, out);
}

// Round 3
// 1509.876 us; speedup vs baseline: 1.5131x; 1.0136x over previous
//
#include <hip/hip_runtime.h>
#include <math.h>

// ---------------------------------------------------------------------------
// RecurrentEncoder: LSTM (B=256, D=2048, H=2048, T=32) + emission head (K=64)
// Round 3: flat-GEMM structure. W (gate-permuted, fragment-transposed) lives
// in LDS (2 x 64KB phases, identity-copy staging, conflict-free reads);
// A (h^T, [k8][row][16B]) streams global->register with a depth-4 ring.
// Block = 256 rows x 32 q-cols, 8 waves x (32row x 32col) wave-tiles.
// ---------------------------------------------------------------------------

typedef short  short8  __attribute__((ext_vector_type(8)));   // 8 x bf16
typedef float  floatx4 __attribute__((ext_vector_type(4)));

#define BB 256
#define HH 2048
#define G4 8192
#define KK 64
#define TT 32

__device__ __forceinline__ unsigned short f2bf(float f) {
  union { float f; unsigned int u; } v; v.f = f;
  unsigned int u = v.u;
  u += 0x7fffu + ((u >> 16) & 1u);   // round-to-nearest-even
  return (unsigned short)(u >> 16);
}
__device__ __forceinline__ float sigmoidf_(float x) { return 1.0f / (1.0f + __expf(-x)); }
__device__ __forceinline__ float softplusf_(float x) {
  return (x > 20.0f) ? x : log1pf(__expf(x));
}
__device__ __forceinline__ short8 cvt8(const float* __restrict__ s) {
  float4 a = reinterpret_cast<const float4*>(s)[0];
  float4 b = reinterpret_cast<const float4*>(s)[1];
  short8 o;
  o[0] = f2bf(a.x); o[1] = f2bf(a.y); o[2] = f2bf(a.z); o[3] = f2bf(a.w);
  o[4] = f2bf(b.x); o[5] = f2bf(b.y); o[6] = f2bf(b.z); o[7] = f2bf(b.w);
  return o;
}

// ---------------------------------------------------------------------------
// Weight transform: fp32 row-major [q or gate-major][K] ->
// bf16 chunks [blk][phase 2][k8 128][col 32][8elem]  (exact LDS slab layout).
// PERM=1: q = u*4+g  ->  src row g*2048+u  (LSTM gate interleave).
// One thread handles 2 k8-chunks (64-B src read, 2 coalesced 16-B writes).
// ---------------------------------------------------------------------------
template <int PERM>
__global__ void cvt_w_kernel(const float* __restrict__ in,
                             unsigned short* __restrict__ out, int total) {
  int tid = blockIdx.x * 256 + threadIdx.x;
  if (tid >= total) return;
  int col = tid & 31;
  int k4  = (tid >> 5) & 63;    // pair index: k8 = 2*k4
  int ph  = (tid >> 11) & 1;
  int blk = tid >> 12;
  int q = blk * 32 + col;
  int srcrow = PERM ? ((q & 3) * HH + (q >> 2)) : q;
  const float* src = in + (size_t)srcrow * HH + (ph * 128 + k4 * 2) * 8;
  short8 o0 = cvt8(src);
  short8 o1 = cvt8(src + 8);
  size_t ch = ((size_t)(blk * 2 + ph) * 128 + k4 * 2) * 32 + col;
  reinterpret_cast<short8*>(out)[ch]      = o0;
  reinterpret_cast<short8*>(out)[ch + 32] = o1;
}

// x fp32 [256][2048] -> x^T chunks [k8 256][row 256][8]
__global__ void cvt_x_kernel(const float* __restrict__ in,
                             unsigned short* __restrict__ out) {
  int tid = blockIdx.x * 256 + threadIdx.x;   // 65536
  int row = tid & 255, k8 = tid >> 8;
  short8 o = cvt8(in + (size_t)row * HH + k8 * 8);
  reinterpret_cast<short8*>(out)[tid] = o;    // chunk = k8*256 + row
}

// ---------------------------------------------------------------------------
// Core GEMM: 256 rows x 32 cols x K2048. 512 threads (8 waves x 32-row tile).
// A8: [k8 256][row 256] 16-B chunks (global, ring-prefetched to regs).
// Wg8: this block's slab [ph 2][k8 128][col 32] chunks (global).
// L8: 64-KB LDS slab (identity copy of one phase).
// acc[rt][ct]: rows rt*16, cols ct*16 of the wave's 32x32 tile.
// ---------------------------------------------------------------------------
__device__ __forceinline__ void core_gemm(const short8* __restrict__ A8,
                                          const short8* __restrict__ Wg8,
                                          short8* L8, floatx4 acc[2][2]) {
  const int tid = threadIdx.x;
  const int lane = tid & 63, wave = tid >> 6;
  const int l15 = lane & 15, l4 = lane >> 4;
  const short8* Lr = L8 + l4 * 32 + l15;          // + kt*128 + ct*16
  const int abase = l4 * 256 + wave * 32 + l15;   // chunk = k8*256 + row (+rt*16)
  for (int ph = 0; ph < 2; ++ph) {
    __syncthreads();   // protect slab from previous phase's readers
#pragma unroll
    for (int j = 0; j < 8; ++j)
      L8[tid + j * 512] = Wg8[ph * 4096 + tid + j * 512];
    __syncthreads();
    short8 Ar[4][2];
#pragma unroll
    for (int i = 0; i < 4; ++i) {
      Ar[i][0] = A8[abase +      (ph * 128 + i * 4) * 256];
      Ar[i][1] = A8[abase + 16 + (ph * 128 + i * 4) * 256];
    }
#pragma unroll
    for (int kt = 0; kt < 32; ++kt) {
      short8 a0 = Ar[kt & 3][0], a1 = Ar[kt & 3][1];
      if (kt < 28) {
        Ar[kt & 3][0] = A8[abase +      (ph * 128 + (kt + 4) * 4) * 256];
        Ar[kt & 3][1] = A8[abase + 16 + (ph * 128 + (kt + 4) * 4) * 256];
      }
      short8 b0 = Lr[kt * 128];
      short8 b1 = Lr[kt * 128 + 16];
      acc[0][0] = __builtin_amdgcn_mfma_f32_16x16x32_bf16(a0, b0, acc[0][0], 0, 0, 0);
      acc[0][1] = __builtin_amdgcn_mfma_f32_16x16x32_bf16(a0, b1, acc[0][1], 0, 0, 0);
      acc[1][0] = __builtin_amdgcn_mfma_f32_16x16x32_bf16(a1, b0, acc[1][0], 0, 0, 0);
      acc[1][1] = __builtin_amdgcn_mfma_f32_16x16x32_bf16(a1, b1, acc[1][1], 0, 0, 0);
    }
  }
}

// ---------------------------------------------------------------------------
// One LSTM tick. Block owns q-cols [32b, 32b+32) = units [8b, 8b+8) x 4 gates.
// Epilogue: + xg, gate activations, shfl-gather i/f/g/o, cell update,
// h written transposed into HallT slot t+1.
// ---------------------------------------------------------------------------
__global__ __launch_bounds__(512) void tick_kernel(
    const unsigned short* __restrict__ HinT, unsigned short* __restrict__ HoutT,
    const unsigned short* __restrict__ Wt2, const float* __restrict__ xg,
    float* __restrict__ c, float* __restrict__ outh, float* __restrict__ outc,
    int last) {
  __shared__ __align__(16) unsigned short Wlds[32768];
  floatx4 acc[2][2];
  floatx4 z4 = {0.f, 0.f, 0.f, 0.f};
  acc[0][0] = z4; acc[0][1] = z4; acc[1][0] = z4; acc[1][1] = z4;
  core_gemm(reinterpret_cast<const short8*>(HinT),
            reinterpret_cast<const short8*>(Wt2) + (size_t)blockIdx.x * 8192,
            reinterpret_cast<short8*>(Wlds), acc);

  const int tid = threadIdx.x, lane = tid & 63, wave = tid >> 6;
  const int l15 = lane & 15, l4 = lane >> 4;
  const int qb = blockIdx.x * 32, rw = wave * 32;
  const int gate = l15 & 3;
  const int base = lane & ~3;
#pragma unroll
  for (int rt = 0; rt < 2; ++rt)
#pragma unroll
    for (int ct = 0; ct < 2; ++ct) {
      const floatx4 av = acc[rt][ct];
      const int q = qb + ct * 16 + l15;
      const int u = q >> 2;
#pragma unroll
      for (int r = 0; r < 4; ++r) {
        const int row = rw + rt * 16 + l4 * 4 + r;
        float g = av[r] + xg[(size_t)row * G4 + q];
        float act = (gate == 2) ? tanhf(g) : sigmoidf_(g);
        float iv = __shfl(act, base);
        float fv = __shfl(act, base + 1);
        float gv = __shfl(act, base + 2);
        float ov = __shfl(act, base + 3);
        if (gate == 0) {
          const size_t ci = (size_t)row * HH + u;
          float cnew = fv * c[ci] + iv * gv;
          float hnew = ov * tanhf(cnew);
          c[ci] = cnew;
          HoutT[(size_t)(blockIdx.x * 256 + row) * 8 + (u & 7)] = f2bf(hnew);
          if (last) { outh[ci] = hnew; outc[ci] = cnew; }
        }
      }
    }
}

// xg = x @ W_ih^T (q-permuted cols) + b_ih + b_hh
__global__ __launch_bounds__(512) void xg_kernel(
    const unsigned short* __restrict__ XT, const unsigned short* __restrict__ Wih,
    const float* __restrict__ b_ih, const float* __restrict__ b_hh,
    float* __restrict__ xg) {
  __shared__ __align__(16) unsigned short Wlds[32768];
  floatx4 acc[2][2];
  floatx4 z4 = {0.f, 0.f, 0.f, 0.f};
  acc[0][0] = z4; acc[0][1] = z4; acc[1][0] = z4; acc[1][1] = z4;
  core_gemm(reinterpret_cast<const short8*>(XT),
            reinterpret_cast<const short8*>(Wih) + (size_t)blockIdx.x * 8192,
            reinterpret_cast<short8*>(Wlds), acc);

  const int tid = threadIdx.x, lane = tid & 63, wave = tid >> 6;
  const int l15 = lane & 15, l4 = lane >> 4;
  const int qb = blockIdx.x * 32, rw = wave * 32;
#pragma unroll
  for (int rt = 0; rt < 2; ++rt)
#pragma unroll
    for (int ct = 0; ct < 2; ++ct) {
      const int q = qb + ct * 16 + l15;
      const float bias = b_ih[(q & 3) * HH + (q >> 2)] + b_hh[(q & 3) * HH + (q >> 2)];
#pragma unroll
      for (int r = 0; r < 4; ++r) {
        const int row = rw + rt * 16 + l4 * 4 + r;
        xg[(size_t)row * G4 + q] = acc[rt][ct][r] + bias;
      }
    }
}

// fe = h_t @ W_fe^T + b_fe for all t: block = (t, colgroup of 32)
__global__ __launch_bounds__(512) void fe_kernel(
    const unsigned short* __restrict__ HallT, const unsigned short* __restrict__ Wfe,
    const float* __restrict__ b_fe, float* __restrict__ fe) {
  const int t = blockIdx.x >> 2, cg = blockIdx.x & 3;
  __shared__ __align__(16) unsigned short Wlds[32768];
  floatx4 acc[2][2];
  floatx4 z4 = {0.f, 0.f, 0.f, 0.f};
  acc[0][0] = z4; acc[0][1] = z4; acc[1][0] = z4; acc[1][1] = z4;
  core_gemm(reinterpret_cast<const short8*>(HallT) + (size_t)(t + 1) * 65536,
            reinterpret_cast<const short8*>(Wfe) + (size_t)cg * 8192,
            reinterpret_cast<short8*>(Wlds), acc);

  const int tid = threadIdx.x, lane = tid & 63, wave = tid >> 6;
  const int l15 = lane & 15, l4 = lane >> 4;
  const int rw = wave * 32;
#pragma unroll
  for (int rt = 0; rt < 2; ++rt)
#pragma unroll
    for (int ct = 0; ct < 2; ++ct) {
      const int col = cg * 32 + ct * 16 + l15;
      const float bias = b_fe[col];
#pragma unroll
      for (int r = 0; r < 4; ++r) {
        const int row = rw + rt * 16 + l4 * 4 + r;
        fe[((size_t)t * 256 + row) * 128 + col] = acc[rt][ct][r] + bias;
      }
    }
}

// z = eps*softplus(fe[:,64:]-5) + fe[:,:64]; outputs laid out (B,K,T)
__global__ void z_kernel(const float* __restrict__ eps, const float* __restrict__ fe,
                         float* __restrict__ out) {
  const int tid = blockIdx.x * blockDim.x + threadIdx.x;  // 524288 = T*B*K
  const int tt = tid >> 14;
  const int b = (tid >> 6) & 255;
  const int k = tid & 63;
  const int frow = tt * 256 + b;
  const float mus = fe[frow * 128 + k];
  const float sig = softplusf_(fe[frow * 128 + 64 + k] - 5.0f);
  const float z = eps[tid] * sig + mus;
  const int o = (b * KK + k) * TT + tt;
  out[o] = z;
  out[524288 + o] = mus;
  out[2 * 524288 + o] = sig;
}

extern "C" void kernel_launch(void* const* d_in, const int* in_sizes, int n_in,
                              void* d_out, int out_size, void* d_ws, size_t ws_size,
                              hipStream_t stream) {
  const float* x    = (const float*)d_in[0];
  const float* eps  = (const float*)d_in[1];
  const float* W_ih = (const float*)d_in[2];
  const float* W_hh = (const float*)d_in[3];
  const float* b_ih = (const float*)d_in[4];
  const float* b_hh = (const float*)d_in[5];
  const float* W_fe = (const float*)d_in[6];
  const float* b_fe = (const float*)d_in[7];
  float* out = (float*)d_out;

  const size_t BH  = (size_t)BB * HH;       // 524288
  const size_t BKT = (size_t)BB * KK * TT;  // 524288

  char* p = (char*)d_ws;
  auto nxt = [&](size_t bytes) -> char* {
    char* r = p; p += (bytes + 255) & ~(size_t)255; return r;
  };
  unsigned short* Wbig  = (unsigned short*)nxt((size_t)G4 * HH * 2);       // 32 MB, W_ih then W_hh
  float*          xg    = (float*)nxt((size_t)BB * G4 * 4);                // 8 MB
  float*          c     = (float*)nxt(BH * 4);                             // 2 MB
  unsigned short* HallT = (unsigned short*)nxt((size_t)(TT + 1) * BH * 2); // 33 MB
  unsigned short* XT    = (unsigned short*)nxt(BH * 2);                    // 1 MB
  unsigned short* Wfeb  = (unsigned short*)nxt((size_t)128 * HH * 2);      // 0.5 MB
  float*          fe    = (float*)nxt((size_t)(TT * BB) * 128 * 4);        // 4 MB

  hipMemsetAsync(c, 0, BH * 4, stream);
  hipMemsetAsync(HallT, 0, BH * 2, stream);  // slot 0 = h0 = 0

  cvt_x_kernel<<<256, 256, 0, stream>>>(x, XT);
  cvt_w_kernel<0><<<64, 256, 0, stream>>>(W_fe, Wfeb, 16384);
  cvt_w_kernel<1><<<4096, 256, 0, stream>>>(W_ih, Wbig, 1048576);
  xg_kernel<<<256, 512, 0, stream>>>(XT, Wbig, b_ih, b_hh, xg);
  cvt_w_kernel<1><<<4096, 256, 0, stream>>>(W_hh, Wbig, 1048576);

  for (int t = 0; t < TT; t++) {
    tick_kernel<<<256, 512, 0, stream>>>(
        HallT + (size_t)t * BH, HallT + (size_t)(t + 1) * BH, Wbig, xg, c,
        out + 3 * BKT, out + 3 * BKT + BH, (int)(t == TT - 1));
  }

  fe_kernel<<<128, 512, 0, stream>>>(HallT, Wfeb, b_fe, fe);
  z_kernel<<<2048, 256, 0, stream>>>(eps, fe, out);
}